// Round 3
// baseline (292.228 us; speedup 1.0000x reference)
//
#include <hip/hip_runtime.h>
#include <hip/hip_bf16.h>

#define B_ 32
#define N_ 2048
#define D_ 512
#define KC_ 64
#define KG_ 80
#define M_ (B_*N_)   // 65536

typedef __attribute__((ext_vector_type(8))) short short8;
typedef __attribute__((ext_vector_type(4))) float f32x4;

// fp32 -> bf16 round-to-nearest-even, bit trick (finite inputs only)
__device__ __forceinline__ unsigned short bf_rn(float f){
  unsigned int u = __float_as_uint(f);
  unsigned int r = u + 0x7FFFu + ((u >> 16) & 1u);
  return (unsigned short)(r >> 16);
}
__device__ __forceinline__ float bf_up(unsigned short h){
  return __uint_as_float(((unsigned int)h) << 16);
}
// 8 fp32 -> hi/lo bf16 frags
__device__ __forceinline__ void cvt8(const float* v, short8& hi, short8& lo){
#pragma unroll
  for (int i=0;i<8;i++){
    unsigned short h = bf_rn(v[i]);
    float rem = v[i] - bf_up(h);
    hi[i] = (short)h;
    lo[i] = (short)bf_rn(rem);
  }
}

// ---------------- K0: clusters -> fragment-ordered bf16 hi/lo --------------
__global__ __launch_bounds__(256) void k0_prep(const float* __restrict__ cl,
                                               unsigned short* __restrict__ Bf)
{
  int tid = blockIdx.x*256 + threadIdx.x;     // 40*256 = 10240
  int l  = tid & 63;
  int hl = (tid >> 6) & 1;
  int j  = (tid >> 7) % 5;
  int c  = tid / 640;
  int kk  = c*32 + (l>>4)*8;
  int col = j*16 + (l&15);
  unsigned short o[8];
#pragma unroll
  for (int jj=0;jj<8;jj++){
    float v = cl[(size_t)(kk+jj)*KG_ + col];
    unsigned short h = bf_rn(v);
    if (hl == 0) o[jj] = h;
    else         o[jj] = bf_rn(v - bf_up(h));
  }
#pragma unroll
  for (int jj=0;jj<8;jj++) Bf[(size_t)tid*8 + jj] = o[jj];
}

// ---------------- K1: a = x @ clusters (MFMA, split-bf16) + col sums -------
// grid 1024 (64 rows), block 256 = 4 waves; wave: 16 rows x 80 cols.
// A frags direct from global with c+1 prefetch; B frags from L2-resident Bf.
__global__ __launch_bounds__(256) void k1_proj(
    const float* __restrict__ x, const unsigned short* __restrict__ Bf,
    float* __restrict__ a, float* __restrict__ S1, float* __restrict__ S2)
{
  __shared__ float ls1[KG_], ls2[KG_];
  const int t = threadIdx.x;
  const int w = t >> 6, lane = t & 63;
  const int m = lane & 15, q = lane >> 4;
  const int row0 = blockIdx.x*64 + w*16;
  if (t < KG_){ ls1[t]=0.f; ls2[t]=0.f; }
  __syncthreads();

  const float* xr = x + (size_t)(row0 + m)*D_ + q*8;

  f32x4 acc[5];
#pragma unroll
  for (int j=0;j<5;j++) acc[j] = (f32x4){0.f,0.f,0.f,0.f};

  float v[8];
  *(float4*)&v[0] = *(const float4*)(xr);
  *(float4*)&v[4] = *(const float4*)(xr + 4);

  for (int c=0;c<16;c++){
    float nv[8];
    if (c < 15){
      *(float4*)&nv[0] = *(const float4*)(xr + (c+1)*32);
      *(float4*)&nv[4] = *(const float4*)(xr + (c+1)*32 + 4);
    }
    const unsigned short* bp = Bf + (size_t)(c*5)*1024 + lane*8;
    short8 bh[5], bl[5];
#pragma unroll
    for (int j=0;j<5;j++){
      bh[j] = *(const short8*)(bp + (size_t)j*1024);
      bl[j] = *(const short8*)(bp + (size_t)j*1024 + 512);
    }
    short8 ah, al;
    cvt8(v, ah, al);
#pragma unroll
    for (int j=0;j<5;j++){
      acc[j] = __builtin_amdgcn_mfma_f32_16x16x32_bf16(ah, bh[j], acc[j], 0,0,0);
      acc[j] = __builtin_amdgcn_mfma_f32_16x16x32_bf16(al, bh[j], acc[j], 0,0,0);
      acc[j] = __builtin_amdgcn_mfma_f32_16x16x32_bf16(ah, bl[j], acc[j], 0,0,0);
    }
    if (c < 15){
#pragma unroll
      for (int i=0;i<8;i++) v[i] = nv[i];
    }
  }

  // epilogue: store a + fused column sums
  float s1v[5], s2v[5];
#pragma unroll
  for (int j=0;j<5;j++){
    f32x4 vv = acc[j];
    size_t base = (size_t)(row0 + q*4)*KG_ + j*16 + m;
    a[base]        = vv[0];
    a[base+KG_]    = vv[1];
    a[base+2*KG_]  = vv[2];
    a[base+3*KG_]  = vv[3];
    s1v[j] = vv[0]+vv[1]+vv[2]+vv[3];
    s2v[j] = vv[0]*vv[0]+vv[1]*vv[1]+vv[2]*vv[2]+vv[3]*vv[3];
  }
#pragma unroll
  for (int j=0;j<5;j++){
    float s1 = s1v[j], s2 = s2v[j];
    s1 += __shfl_xor(s1,16); s1 += __shfl_xor(s1,32);
    s2 += __shfl_xor(s2,16); s2 += __shfl_xor(s2,32);
    if (q == 0){
      atomicAdd(&ls1[j*16+m], s1);
      atomicAdd(&ls2[j*16+m], s2);
    }
  }
  __syncthreads();
  if (t < KG_){ atomicAdd(&S1[t], ls1[t]); atomicAdd(&S2[t], ls2[t]); }
}

// ---------------- K2: BN finalize -> scale/shift ----------------
__global__ void k2_bn(const float* __restrict__ S1, const float* __restrict__ S2,
                      const float* __restrict__ gamma, const float* __restrict__ beta,
                      float* __restrict__ scale, float* __restrict__ shift)
{
  int t = threadIdx.x;
  if (t < KG_){
    const float invM = 1.0f / (float)M_;
    float mean = S1[t] * invM;
    float var  = S2[t] * invM - mean*mean;
    float sc = gamma[t] * rsqrtf(var + 1e-5f);
    scale[t] = sc;
    shift[t] = beta[t] - mean*sc;
  }
}

// ---------------- K3: BN affine + softmax (in-place p into a) + a_sum ------
__global__ __launch_bounds__(256) void k3_softmax(
    float* __restrict__ a, const float* __restrict__ scale,
    const float* __restrict__ shift, float* __restrict__ asum)
{
  __shared__ float as[64*84];
  __shared__ float sc[KG_], sh[KG_];
  __shared__ float lsum[KC_];
  const int t = threadIdx.x;
  const int row0 = blockIdx.x * 64;
  if (t < KG_){ sc[t]=scale[t]; sh[t]=shift[t]; }
  if (t < KC_) lsum[t]=0.f;
  __syncthreads();
#pragma unroll
  for (int l=0;l<20;l++){
    int idx = t + 256*l;
    int r = idx/80, col = idx - r*80;
    float v = a[(size_t)(row0+r)*KG_ + col];
    as[r*84+col] = v*sc[col] + sh[col];
  }
  __syncthreads();
  const int rt = t >> 2;
  const int g  = t & 3;
  float m = -1e30f;
#pragma unroll
  for (int c=0;c<20;c++) m = fmaxf(m, as[rt*84 + g + 4*c]);
  m = fmaxf(m, __shfl_xor(m,1));
  m = fmaxf(m, __shfl_xor(m,2));
  float e[20]; float s = 0.f;
#pragma unroll
  for (int c=0;c<20;c++){ float v = __expf(as[rt*84 + g + 4*c] - m); e[c]=v; s+=v; }
  s += __shfl_xor(s,1);
  s += __shfl_xor(s,2);
  const float inv = 1.f/s;
#pragma unroll
  for (int c=0;c<16;c++){
    int col = g + 4*c;
    float pv = e[c]*inv;
    a[(size_t)(row0+rt)*KG_ + col] = pv;
    float su = pv;
    su += __shfl_xor(su,4);  su += __shfl_xor(su,8);
    su += __shfl_xor(su,16); su += __shfl_xor(su,32);
    if ((t&63) < 4) atomicAdd(&lsum[col], su);
  }
  __syncthreads();
  if (t < KC_) atomicAdd(&asum[(blockIdx.x>>5)*KC_ + t], lsum[t]);
}

// ---------------- K4: vlad partials (MFMA, split-bf16, double-buffered) ----
// grid 1024 = 32 b * 8 dtiles(64) * 4 nsplits(512). block 256 = 4 waves.
__global__ __launch_bounds__(256) void k4_vlad(
    const float* __restrict__ x, const float* __restrict__ p, float* __restrict__ vp)
{
  __shared__ unsigned short xh[2][64*40], xl[2][64*40];
  __shared__ unsigned short ph[2][64*40], pl[2][64*40];
  const int t = threadIdx.x;
  const int blk = blockIdx.x;
  const int ns = blk & 3;
  const int dt = (blk >> 2) & 7;
  const int b  = blk >> 5;
  const int w = t >> 6, lane = t & 63;
  const int m = lane & 15, q = lane >> 4;
  const int d0 = dt*64;
  const int nbase = ns*512;
  const int dloc = t & 63, ng = t >> 6;

  const float* xbase = x + ((size_t)b*N_ + nbase)*D_ + d0 + dloc;
  const float* pbase = p + ((size_t)b*N_ + nbase)*KG_ + dloc;

  f32x4 acc[4];
#pragma unroll
  for (int j=0;j<4;j++) acc[j] = (f32x4){0.f,0.f,0.f,0.f};

  // stage chunk 0 into buffer 0
  {
    float xv[8], pv[8];
#pragma unroll
    for (int jj=0;jj<8;jj++){
      xv[jj] = xbase[(size_t)(ng*8+jj)*D_];
      pv[jj] = pbase[(size_t)(ng*8+jj)*KG_];
    }
    short8 hi, lo;
    cvt8(xv, hi, lo);
    *(short8*)&xh[0][dloc*40 + ng*8] = hi;
    *(short8*)&xl[0][dloc*40 + ng*8] = lo;
    cvt8(pv, hi, lo);
    *(short8*)&ph[0][dloc*40 + ng*8] = hi;
    *(short8*)&pl[0][dloc*40 + ng*8] = lo;
  }
  __syncthreads();

  for (int ch=0; ch<16; ch++){
    const int cur = ch & 1;
    float nxv[8], npv[8];
    if (ch < 15){
      const float* xp2 = xbase + (size_t)((ch+1)*32)*D_;
      const float* pp2 = pbase + (size_t)((ch+1)*32)*KG_;
#pragma unroll
      for (int jj=0;jj<8;jj++){
        nxv[jj] = xp2[(size_t)(ng*8+jj)*D_];
        npv[jj] = pp2[(size_t)(ng*8+jj)*KG_];
      }
    }
    short8 ahi = *(const short8*)&xh[cur][(w*16+m)*40 + q*8];
    short8 alo = *(const short8*)&xl[cur][(w*16+m)*40 + q*8];
#pragma unroll
    for (int j=0;j<4;j++){
      short8 bhi = *(const short8*)&ph[cur][(j*16+m)*40 + q*8];
      short8 blo = *(const short8*)&pl[cur][(j*16+m)*40 + q*8];
      acc[j] = __builtin_amdgcn_mfma_f32_16x16x32_bf16(ahi, bhi, acc[j], 0,0,0);
      acc[j] = __builtin_amdgcn_mfma_f32_16x16x32_bf16(alo, bhi, acc[j], 0,0,0);
      acc[j] = __builtin_amdgcn_mfma_f32_16x16x32_bf16(ahi, blo, acc[j], 0,0,0);
    }
    if (ch < 15){
      short8 hi, lo;
      cvt8(nxv, hi, lo);
      *(short8*)&xh[cur^1][dloc*40 + ng*8] = hi;
      *(short8*)&xl[cur^1][dloc*40 + ng*8] = lo;
      cvt8(npv, hi, lo);
      *(short8*)&ph[cur^1][dloc*40 + ng*8] = hi;
      *(short8*)&pl[cur^1][dloc*40 + ng*8] = lo;
    }
    __syncthreads();
  }
#pragma unroll
  for (int j=0;j<4;j++){
    f32x4 v = acc[j];
    size_t base = (((size_t)ns*B_ + b)*D_ + d0 + w*16 + q*4)*KC_ + j*16 + m;
    vp[base]         = v[0];
    vp[base +   KC_] = v[1];
    vp[base + 2*KC_] = v[2];
    vp[base + 3*KC_] = v[3];
  }
}

// ---------------- K5: combine 4 splits, subtract, intra+global L2 norm -----
__global__ __launch_bounds__(1024) void k5_norm(
    const float* __restrict__ vp, const float* __restrict__ c2,
    const float* __restrict__ asum, float* __restrict__ out)
{
  __shared__ float part[16][64];
  __shared__ float invd[64];
  __shared__ float gi_s;
  const int b = blockIdx.x;
  const int t = threadIdx.x;
  const int k = t & 63, dg = t >> 6;
  const float av = asum[b*KC_ + k];
  const size_t stride = (size_t)B_*D_*KC_;
  float v[32];
  float ss = 0.f;
#pragma unroll
  for (int s=0;s<32;s++){
    int d = dg + 16*s;
    size_t idx = ((size_t)b*D_ + d)*KC_ + k;
    float vv = 0.f;
#pragma unroll
    for (int nsp=0;nsp<4;nsp++) vv += vp[idx + (size_t)nsp*stride];
    vv -= c2[d*KC_ + k]*av;
    v[s] = vv;
    ss += vv*vv;
  }
  part[dg][k] = ss;
  __syncthreads();
  if (t < 64){
    float n2 = 0.f;
#pragma unroll
    for (int i=0;i<16;i++) n2 += part[i][t];
    float nn = sqrtf(n2);
    float denom = fmaxf(nn, 1e-12f);
    invd[t] = 1.f/denom;
    float ratio = nn/denom;
    float r2 = ratio*ratio;
#pragma unroll
    for (int mm=1;mm<64;mm<<=1) r2 += __shfl_xor(r2, mm);
    if (t==0){
      float g = sqrtf(r2);
      gi_s = 1.f/fmaxf(g, 1e-12f);
    }
  }
  __syncthreads();
  const float gi = gi_s;
  const float ik = invd[k];
#pragma unroll
  for (int s=0;s<32;s++){
    int d = dg + 16*s;
    out[(size_t)b*(D_*KC_) + (size_t)d*KC_ + k] = v[s]*ik*gi;
  }
}

extern "C" void kernel_launch(void* const* d_in, const int* in_sizes, int n_in,
                              void* d_out, int out_size, void* d_ws, size_t ws_size,
                              hipStream_t stream)
{
  const float* x     = (const float*)d_in[0];
  const float* cl    = (const float*)d_in[1];
  const float* c2    = (const float*)d_in[2];
  const float* gamma = (const float*)d_in[3];
  const float* beta  = (const float*)d_in[4];
  float* out = (float*)d_out;
  float* ws  = (float*)d_ws;

  float* S1    = ws;
  float* S2    = ws + 80;
  float* scale = ws + 160;
  float* shift = ws + 240;
  float* asum  = ws + 320;
  unsigned short* Bf = (unsigned short*)(ws + 4096);
  float* a     = ws + 45056;
  float* vp    = a + (size_t)M_*KG_;

  hipMemsetAsync(ws, 0, 2368*sizeof(float), stream);
  k0_prep   <<<40,   256, 0, stream>>>(cl, Bf);
  k1_proj   <<<1024, 256, 0, stream>>>(x, Bf, a, S1, S2);
  k2_bn     <<<1,    128, 0, stream>>>(S1, S2, gamma, beta, scale, shift);
  k3_softmax<<<1024, 256, 0, stream>>>(a, scale, shift, asum);
  k4_vlad   <<<1024, 256, 0, stream>>>(x, a, vp);
  k5_norm   <<<32,  1024, 0, stream>>>(vp, c2, asum, out);
}